// Round 5
// baseline (60.289 us; speedup 1.0000x reference)
//
#include <hip/hip_runtime.h>
#include <math.h>

// ---------------------------------------------------------------------------
// CNN_88098369175791 — 8-WG, 2 grid barriers, latency-focused R5.
// Key change vs R4: ALL weights needed after a grid barrier are prefetched
// into LDS (or registers) BEFORE the barrier, during P0 — the gbar acquire
// fence invalidates L1/L2, so post-barrier global reads were cold-miss
// serial stalls. Head restructured: out1_w lives in WG0 registers.
// ---------------------------------------------------------------------------

#define NWG 8
#define NT  1024

constexpr int WLEN = 140;
constexpr int TDN  = 14;
constexpr int NOFC = 119;

// ---------------- global arena (floats; at d_ws + 512 B) -------------------
constexpr int G_V16 = 0;     // [32]  vA|vB
constexpr int G_O   = 64;    // [4][119][16]

// ---------------- LDS arena (floats, per-WG, time-multiplexed) -------------
constexpr int EEG = 0;      // [16][119] live P0..LN
constexpr int WA  = 1904;   // 140
constexpr int WB  = 2044;   // 140
// P1 scratch (dead after v16):
constexpr int KPL = 2184;   // [14][119]
constexpr int VPL = 3850;   // [14][119]
constexpr int QPL = 5516;   // [4][119]
constexpr int SC  = 5992;   // [4][14]
constexpr int AVL = 6048;   // [4][119]
constexpr int WT4 = 6524;   // [4][119]
constexpr int MM  = 7000;   // [4][16] -> 7064
// P3 (over P1 scratch): each WG stores only the proj matrix it needs.
constexpr int PRJ = 2184;   // [119][16]  (PAT for WG0-3, PBT for WG4-7)
constexpr int LNT = 4088;   // [119][16] -> 5992
// cm arena:
constexpr int CKL = 5992;   // [119][20] (padded rows: bank-conflict dodge)
constexpr int CVL = 8372;   // [119][20]
constexpr int CQL = 10752;  // [60][16] -> 11712
constexpr int SMB = 11712;  // weight[16]; mi at +16 -> 11729
// head (WG0, post-gbar1; PRJ dead):
constexpr int DD  = 2184;   // 238 (+2 zero pad)
constexpr int HH  = 2426;   // 119
// ---- prefetched weights (live whole kernel) ----
constexpr int CMW = 11730;  // 768  cm_in_w[m]
constexpr int CMB = 12498;  // 48
constexpr int COW = 12546;  // 256  cm_out_w[m]
constexpr int COB = 12802;  // 16
constexpr int MXW = 12818;  // 512  max_fc_w TRANSPOSED [c][t]
constexpr int MXB = 13330;  // 16
constexpr int MCW = 13346;  // 32
constexpr int MCB = 13378;  // 2
constexpr int PRW = 13380;  // 32
constexpr int LNG = 13412;  // 16
constexpr int LNB2= 13428;  // 16
constexpr int FCW = 13444;  // 2
constexpr int FCB = 13446;  // 2
constexpr int O2W = 13448;  // 238 (WG0)
constexpr int O2B = 13686;  // 2
constexpr int O1B = 13688;  // 119 (WG0)
constexpr int TIB = 13807;  // 357
constexpr int TOB = 14164;  // 119
constexpr int ARENA = 14284; // 57,136 B

struct Args {
  const float *x, *td_in_w, *td_in_b, *td_out_w, *td_out_b;
  const float *cm_in_w, *cm_in_b, *cm_out_w, *cm_out_b;
  const float *mc_w, *mc_b, *max_fc_w, *max_fc_b, *proj_w;
  const float *ln_g, *ln_b, *fc_w, *fc_b;
  const float *out1_w, *out1_b, *out2_w, *out2_b;
  float *out;
  unsigned int *bar;   // d_ws (2 sites x 64B, memset to 0 per call)
  float *G;            // d_ws + 512
};

__device__ __forceinline__ float sigmf(float v) {
  return 1.0f / (1.0f + __expf(-v));
}

// device-scope grid barrier; relaxed poll + one trailing acquire fence.
__device__ __forceinline__ void gbar(unsigned int* p) {
  __syncthreads();
  if (threadIdx.x == 0) {
    __hip_atomic_fetch_add(p, 1u, __ATOMIC_ACQ_REL, __HIP_MEMORY_SCOPE_AGENT);
    while (__hip_atomic_load(p, __ATOMIC_RELAXED, __HIP_MEMORY_SCOPE_AGENT) < (unsigned)NWG) {
      __builtin_amdgcn_s_sleep(1);
    }
    __builtin_amdgcn_fence(__ATOMIC_ACQUIRE, "agent");
  }
  __syncthreads();
}

__global__ __launch_bounds__(NT) void fused_cnn_kernel(Args a) {
  __shared__ __align__(16) float S[ARENA];
  const int tid = threadIdx.x;
  const int wgid = blockIdx.x;
  const int grp = tid >> 4;        // 64 groups of 16
  const int lane16 = tid & 15;
  float* G = a.G;

  const int ab = wgid >> 2;          // td stream: WG 0-3 -> A, 4-7 -> B
  const int i0 = (wgid * 4) & 15;    // this WG's 4 q-rows / v16 slots
  const int m  = wgid >> 1;          // this WG's cm-MHA
  const int r0 = (wgid & 1) ? 60 : 0;
  const int nr = (wgid & 1) ? 59 : 60;

  // ---- WG0: out1_w -> registers (issued first; hides HBM latency) ------
  float w1r[30];
  {
    const int r = tid >> 3, oct = tid & 7;
    if (wgid == 0 && r < NOFC) {
#pragma unroll
      for (int i = 0; i < 30; ++i) {
        int c = oct * 30 + i;
        w1r[i] = (c < 238) ? a.out1_w[r * 238 + c] : 0.0f;
      }
    } else {
#pragma unroll
      for (int i = 0; i < 30; ++i) w1r[i] = 0.0f;
    }
  }

  // ---- P0: stage x + prefetch ALL post-barrier weights into LDS --------
  for (int t = tid; t < 16 * NOFC; t += NT) {
    int c = t / NOFC, tt = t - c * NOFC;
    S[EEG + t] = a.x[(1 + c) * WLEN + (WLEN - NOFC) + tt];
  }
  if (tid < WLEN) {
    S[WA + tid] = a.x[tid];
    S[WB + tid] = a.x[17 * WLEN + tid];
  }
  if (tid < 768) S[CMW + tid] = a.cm_in_w[m * 768 + tid];
  if (tid < 48)  S[CMB + tid] = a.cm_in_b[m * 48 + tid];
  if (tid < 256) S[COW + tid] = a.cm_out_w[m * 256 + tid];
  if (tid < 16)  S[COB + tid] = a.cm_out_b[m * 16 + tid];
  if (tid < 512) {                 // max_fc_w transposed: [c][t]
    int t16 = tid >> 5, c32 = tid & 31;
    S[MXW + c32 * 16 + t16] = a.max_fc_w[tid];
  }
  if (tid < 16)  S[MXB + tid] = a.max_fc_b[tid];
  if (tid < 32)  S[MCW + tid] = a.mc_w[tid];
  if (tid < 2)   S[MCB + tid] = a.mc_b[tid];
  if (tid < 32)  S[PRW + tid] = a.proj_w[tid];
  if (tid < 16)  S[LNG + tid] = a.ln_g[tid];
  if (tid < 16)  S[LNB2 + tid] = a.ln_b[tid];
  if (tid < 2)   S[FCW + tid] = a.fc_w[tid];
  if (tid < 2)   S[FCB + tid] = a.fc_b[tid];
  if (wgid == 0) {
    if (tid < 238) S[O2W + tid] = a.out2_w[tid];
    if (tid < 2)   S[O2B + tid] = a.out2_b[tid];
    if (tid < NOFC) S[O1B + tid] = a.out1_b[tid];
  }
  if (tid < 357) S[TIB + tid] = a.td_in_b[tid];
  if (tid < NOFC) S[TOB + tid] = a.td_out_b[tid];
  __syncthreads();

  // ---- P1: kp/vp (this ab, full) + qp (this WG's 4 rows) ---------------
  {
    const float* xb = S + (ab ? WB : WA);
    for (int task = grp; task < 357; task += 64) {
      int typ = (task < 119) ? 0 : (task < 238) ? 1 : 2;  // kp, vp, qp
      int e = task - ((typ == 0) ? 0 : (typ == 1) ? 119 : 238);
      int row = ((typ == 0) ? NOFC : (typ == 1) ? 2 * NOFC : 0) + e;
      const float* wrow = a.td_in_w + row * NOFC;
      float w0 = wrow[lane16], w1 = wrow[lane16 + 16], w2 = wrow[lane16 + 32],
            w3 = wrow[lane16 + 48], w4 = wrow[lane16 + 64], w5 = wrow[lane16 + 80],
            w6 = wrow[lane16 + 96];
      float wt = (lane16 < 7) ? wrow[112 + lane16] : 0.0f;
      float b = S[TIB + row];
      if (typ < 2) {
        for (int j = 0; j < TDN; ++j) {
          const float* x = xb + j;
          float acc = w0 * x[lane16] + w1 * x[lane16 + 16] + w2 * x[lane16 + 32]
                    + w3 * x[lane16 + 48] + w4 * x[lane16 + 64] + w5 * x[lane16 + 80]
                    + w6 * x[lane16 + 96];
          if (lane16 < 7) acc += wt * x[112 + lane16];
#pragma unroll
          for (int mm = 1; mm < 16; mm <<= 1) acc += __shfl_xor(acc, mm);
          if (lane16 == 0) S[(typ ? VPL : KPL) + j * NOFC + e] = acc + b;
        }
      } else {
        for (int q = 0; q < 4; ++q) {
          const float* x = S + EEG + (i0 + q) * NOFC;
          float acc = w0 * x[lane16] + w1 * x[lane16 + 16] + w2 * x[lane16 + 32]
                    + w3 * x[lane16 + 48] + w4 * x[lane16 + 64] + w5 * x[lane16 + 80]
                    + w6 * x[lane16 + 96];
          if (lane16 < 7) acc += wt * x[112 + lane16];
#pragma unroll
          for (int mm = 1; mm < 16; mm <<= 1) acc += __shfl_xor(acc, mm);
          if (lane16 == 0) S[QPL + q * NOFC + e] = acc + b;
        }
      }
    }
  }
  __syncthreads();

  // ---- scores 4x14 ------------------------------------------------------
  if (grp < 56) {
    int q = grp / TDN, j = grp - q * TDN;
    const float* qr = S + QPL + q * NOFC;
    const float* kr = S + KPL + j * NOFC;
    float acc = 0.f;
#pragma unroll
    for (int t = 0; t < 7; ++t) acc += qr[lane16 + 16 * t] * kr[lane16 + 16 * t];
    if (lane16 < 7) acc += qr[112 + lane16] * kr[112 + lane16];
#pragma unroll
    for (int mm = 1; mm < 16; mm <<= 1) acc += __shfl_xor(acc, mm);
    if (lane16 == 0) S[SC + q * TDN + j] = acc * 0.09166984970282113f;
  }
  __syncthreads();

  // ---- softmax (4 rows) -------------------------------------------------
  if (tid < 4) {
    float* r = S + SC + tid * TDN;
    float mx = r[0];
#pragma unroll
    for (int j = 1; j < TDN; ++j) mx = fmaxf(mx, r[j]);
    float sum = 0.f;
#pragma unroll
    for (int j = 0; j < TDN; ++j) { float p = __expf(r[j] - mx); r[j] = p; sum += p; }
    float inv = 1.0f / sum;
#pragma unroll
    for (int j = 0; j < TDN; ++j) r[j] *= inv;
  }
  __syncthreads();

  // ---- av = attn @ vp : 4x119 ------------------------------------------
  for (int o = tid; o < 476; o += NT) {
    int q = o / NOFC, e = o - q * NOFC;
    float acc = 0.f;
#pragma unroll
    for (int j = 0; j < TDN; ++j) acc += S[SC + q * TDN + j] * S[VPL + j * NOFC + e];
    S[AVL + o] = acc;
  }
  __syncthreads();

  // ---- watt rows: 119 weight-reuse tasks, 4 dots each -------------------
  for (int e = grp; e < NOFC; e += 64) {
    const float* wrow = a.td_out_w + e * NOFC;
    float w0 = wrow[lane16], w1 = wrow[lane16 + 16], w2 = wrow[lane16 + 32],
          w3 = wrow[lane16 + 48], w4 = wrow[lane16 + 64], w5 = wrow[lane16 + 80],
          w6 = wrow[lane16 + 96];
    float wt = (lane16 < 7) ? wrow[112 + lane16] : 0.0f;
    float b = S[TOB + e];
    for (int q = 0; q < 4; ++q) {
      const float* x = S + AVL + q * NOFC;
      float acc = w0 * x[lane16] + w1 * x[lane16 + 16] + w2 * x[lane16 + 32]
                + w3 * x[lane16 + 48] + w4 * x[lane16 + 64] + w5 * x[lane16 + 80]
                + w6 * x[lane16 + 96];
      if (lane16 < 7) acc += wt * x[112 + lane16];
#pragma unroll
      for (int mm = 1; mm < 16; mm <<= 1) acc += __shfl_xor(acc, mm);
      if (lane16 == 0) S[WT4 + q * NOFC + e] = acc + b;
    }
  }
  __syncthreads();

  // ---- M[q][i] = eeg[i] . watt[q]  (exactly 64 dots) --------------------
  {
    int q = grp >> 4, i = grp & 15;
    const float* xr = S + EEG + i * NOFC;
    const float* wr = S + WT4 + q * NOFC;
    float acc = 0.f;
#pragma unroll
    for (int t = 0; t < 7; ++t) acc += xr[lane16 + 16 * t] * wr[lane16 + 16 * t];
    if (lane16 < 7) acc += xr[112 + lane16] * wr[112 + lane16];
#pragma unroll
    for (int mm = 1; mm < 16; mm <<= 1) acc += __shfl_xor(acc, mm);
    if (lane16 == 0) S[MM + q * 16 + i] = acc;
  }
  __syncthreads();

  // ---- v16 slots for this WG -> global ----------------------------------
  if (tid < 4) {
    float acc = S[MCB + ab];
#pragma unroll
    for (int i = 0; i < 16; ++i) acc += S[MCW + ab * 16 + i] * S[MM + tid * 16 + i];
    G[G_V16 + ab * 16 + i0 + tid] = fmaxf(acc, 0.f);
  }
  gbar(a.bar + 0);

  // ---- weight + argmax (replicated; all-LDS weights) --------------------
  if (tid < 16) {
    float acc = S[MXB + tid];
#pragma unroll
    for (int c = 0; c < 32; ++c) acc += S[MXW + c * 16 + tid] * G[G_V16 + c];
    S[SMB + tid] = fmaxf(acc, 0.f);
  }
  __syncthreads();
  if (tid == 0) {
    float best = S[SMB]; int mi = 0;
    for (int r = 1; r < 16; ++r) {
      float w = S[SMB + r];
      if (w > best) { best = w; mi = r; }
    }
    if (mi > TDN - 1) mi = TDN - 1;   // jnp.take clamps OOB
    S[SMB + 16] = (float)mi;
  }
  __syncthreads();

  // ---- P3: PRJ (only the one this WG needs) + LNT -----------------------
  {
    const int mi = (int)S[SMB + 16];
    const int abp = wgid >> 2;   // 0-3 need PAT (proj row 0), 4-7 PBT (row 1)
    for (int o = tid; o < 1904; o += NT) {
      int t = o >> 4, c = o & 15;
      S[PRJ + o] = S[PRW + abp * 16 + c] * S[(abp ? WB : WA) + t + mi];
    }
    if (tid < NOFC) {
      float xv[16];
      float mu = 0.f;
#pragma unroll
      for (int c = 0; c < 16; ++c) { xv[c] = S[EEG + c * NOFC + tid]; mu += xv[c]; }
      mu *= (1.0f / 16.0f);
      float var = 0.f;
#pragma unroll
      for (int c = 0; c < 16; ++c) { float d = xv[c] - mu; var += d * d; }
      var *= (1.0f / 16.0f);
      float inv = 1.0f / sqrtf(var + 1e-5f);
#pragma unroll
      for (int c = 0; c < 16; ++c)
        S[LNT + tid * 16 + c] = (xv[c] - mu) * inv * S[LNG + c] + S[LNB2 + c];
    }
  }
  __syncthreads();

  // ---- cm qkv: K,V full + Q rows for this WG (all-LDS) ------------------
  {
    // data/kv sources: m0: d=PRJ,k=LNT | m1: d=LNT,k=PRJ | m2: d=LNT,k=PRJ | m3: d=PRJ,k=LNT
    const int dsrc = (m == 0 || m == 3) ? PRJ : LNT;
    const int ksrc = (m == 0 || m == 3) ? LNT : PRJ;
    const int nout = 3808 + nr * 16;
    for (int o = tid; o < nout; o += NT) {
      int which, t, e, src, dst;
      if (o < 1904)      { which = 1; t = o >> 4;          e = o & 15; src = ksrc; dst = CKL + t * 20 + e; }
      else if (o < 3808) { int r1 = o - 1904; which = 2; t = r1 >> 4; e = r1 & 15; src = ksrc; dst = CVL + t * 20 + e; }
      else               { int r1 = o - 3808; which = 0; t = r0 + (r1 >> 4); e = r1 & 15; src = dsrc; dst = CQL + (r1 >> 4) * 16 + e; }
      const float4* sa = (const float4*)(S + src + t * 16);
      const float4* wr = (const float4*)(S + CMW + (which * 16 + e) * 16);
      float4 s0 = sa[0], s1 = sa[1], s2 = sa[2], s3 = sa[3];
      float4 q0 = wr[0], q1 = wr[1], q2 = wr[2], q3 = wr[3];
      float d0 = s0.x * q0.x + s0.y * q0.y + s0.z * q0.z + s0.w * q0.w;
      float d1 = s1.x * q1.x + s1.y * q1.y + s1.z * q1.z + s1.w * q1.w;
      float d2 = s2.x * q2.x + s2.y * q2.y + s2.z * q2.z + s2.w * q2.w;
      float d3 = s3.x * q3.x + s3.y * q3.y + s3.z * q3.z + s3.w * q3.w;
      S[dst] = S[CMB + which * 16 + e] + ((d0 + d1) + (d2 + d3));
    }
  }
  __syncthreads();

  // ---- cm attention: one row per 16-lane group --------------------------
  if (grp < nr) {
    const int r = r0 + grp;
    float qv[16];
    {
      const float* qg = S + CQL + grp * 16;
#pragma unroll
      for (int e = 0; e < 16; ++e) qv[e] = qg[e];
    }
    float p[8];
    float mx = -1e30f;
#pragma unroll
    for (int cc = 0; cc < 8; ++cc) {
      int u = lane16 + cc * 16;
      int uc = (u < NOFC) ? u : 0;
      const float4* k4 = (const float4*)(S + CKL + uc * 20);
      float4 k0 = k4[0], k1 = k4[1], k2 = k4[2], k3 = k4[3];
      float d0 = qv[0]*k0.x + qv[1]*k0.y + qv[2]*k0.z + qv[3]*k0.w;
      float d1 = qv[4]*k1.x + qv[5]*k1.y + qv[6]*k1.z + qv[7]*k1.w;
      float d2 = qv[8]*k2.x + qv[9]*k2.y + qv[10]*k2.z + qv[11]*k2.w;
      float d3 = qv[12]*k3.x + qv[13]*k3.y + qv[14]*k3.z + qv[15]*k3.w;
      float sc = ((d0 + d1) + (d2 + d3)) * 0.25f;
      p[cc] = (u < NOFC) ? sc : -1e30f;
      mx = fmaxf(mx, p[cc]);
    }
#pragma unroll
    for (int d = 1; d < 16; d <<= 1) mx = fmaxf(mx, __shfl_xor(mx, d));
    float sum = 0.f;
#pragma unroll
    for (int cc = 0; cc < 8; ++cc) { p[cc] = __expf(p[cc] - mx); sum += p[cc]; }
#pragma unroll
    for (int d = 1; d < 16; d <<= 1) sum += __shfl_xor(sum, d);
    float inv = 1.0f / sum;

    float oa[16];
#pragma unroll
    for (int e = 0; e < 16; ++e) oa[e] = 0.f;
#pragma unroll
    for (int cc = 0; cc < 8; ++cc) {
      int u = lane16 + cc * 16;
      if (u < NOFC) {
        const float4* v4 = (const float4*)(S + CVL + u * 20);
        float4 v0 = v4[0], v1 = v4[1], v2 = v4[2], v3 = v4[3];
        float pv = p[cc];
        oa[0] += pv*v0.x; oa[1] += pv*v0.y; oa[2] += pv*v0.z; oa[3] += pv*v0.w;
        oa[4] += pv*v1.x; oa[5] += pv*v1.y; oa[6] += pv*v1.z; oa[7] += pv*v1.w;
        oa[8] += pv*v2.x; oa[9] += pv*v2.y; oa[10] += pv*v2.z; oa[11] += pv*v2.w;
        oa[12] += pv*v3.x; oa[13] += pv*v3.y; oa[14] += pv*v3.z; oa[15] += pv*v3.w;
      }
    }
#pragma unroll
    for (int e = 0; e < 16; ++e) {
#pragma unroll
      for (int d = 1; d < 16; d <<= 1) oa[e] += __shfl_xor(oa[e], d);
      oa[e] *= inv;
    }
    {
      const float* ow = S + COW + lane16 * 16;
      float acc = S[COB + lane16];
#pragma unroll
      for (int e = 0; e < 16; ++e) acc += oa[e] * ow[e];
      G[G_O + (m * NOFC + r) * 16 + lane16] = acc;
    }
  }
  gbar(a.bar + 16);

  // ---- head (WG0 only; weights already in regs/LDS) ---------------------
  if (wgid == 0) {
    for (int o = tid; o < 2 * NOFC; o += NT) {
      int half = o / NOFC, t = o - half * NOFC;
      const float* A = G + G_O + ((half ? 3 : 0) * NOFC + t) * 16;
      const float* B = G + G_O + ((half ? 2 : 1) * NOFC + t) * 16;
      float acc = 0.f;
#pragma unroll
      for (int c = 0; c < 16; ++c) acc += A[c] * B[c];
      S[DD + o] = sigmf(S[FCW + half] * acc + S[FCB + half]);
    }
    if (tid < 2) S[DD + 238 + tid] = 0.0f;   // pad so oct-7 overreads are 0*0
    __syncthreads();
    {
      const int r = tid >> 3, oct = tid & 7;
      if (r < NOFC) {
        float acc = 0.f;
#pragma unroll
        for (int i = 0; i < 30; ++i) acc += w1r[i] * S[DD + oct * 30 + i];
        acc += __shfl_xor(acc, 1);
        acc += __shfl_xor(acc, 2);
        acc += __shfl_xor(acc, 4);
        if (oct == 0) S[HH + r] = sigmf(acc + S[O1B + r]);
      }
    }
    __syncthreads();
    if (tid < 32) {
      int o2 = tid >> 4;
      float a0 = 0.f;
#pragma unroll
      for (int t = 0; t < 8; ++t) {
        int idx = lane16 + 16 * t;
        if (idx < NOFC) a0 += S[O2W + o2 * NOFC + idx] * S[HH + idx];
      }
      float acc = a0;
#pragma unroll
      for (int mm = 1; mm < 16; mm <<= 1) acc += __shfl_xor(acc, mm);
      if (lane16 == 0) a.out[o2] = sigmf(acc + S[O2B + o2]);
    }
  }
}

extern "C" void kernel_launch(void* const* d_in, const int* in_sizes, int n_in,
                              void* d_out, int out_size, void* d_ws, size_t ws_size,
                              hipStream_t stream) {
  Args a;
  a.x        = (const float*)d_in[0];
  a.td_in_w  = (const float*)d_in[1];
  a.td_in_b  = (const float*)d_in[2];
  a.td_out_w = (const float*)d_in[3];
  a.td_out_b = (const float*)d_in[4];
  a.cm_in_w  = (const float*)d_in[5];
  a.cm_in_b  = (const float*)d_in[6];
  a.cm_out_w = (const float*)d_in[7];
  a.cm_out_b = (const float*)d_in[8];
  a.mc_w     = (const float*)d_in[9];
  a.mc_b     = (const float*)d_in[10];
  a.max_fc_w = (const float*)d_in[11];
  a.max_fc_b = (const float*)d_in[12];
  a.proj_w   = (const float*)d_in[13];
  a.ln_g     = (const float*)d_in[14];
  a.ln_b     = (const float*)d_in[15];
  a.fc_w     = (const float*)d_in[16];
  a.fc_b     = (const float*)d_in[17];
  a.out1_w   = (const float*)d_in[18];
  a.out1_b   = (const float*)d_in[19];
  a.out2_w   = (const float*)d_in[20];
  a.out2_b   = (const float*)d_in[21];
  a.out      = (float*)d_out;
  a.bar      = (unsigned int*)d_ws;
  a.G        = (float*)((char*)d_ws + 512);

  // zero the 2 barrier counters (64 B apart) every call — graph replays this.
  hipMemsetAsync(d_ws, 0, 512, stream);
  fused_cnn_kernel<<<dim3(NWG), dim3(NT), 0, stream>>>(a);
}

// Round 6
// 36.049 us; speedup vs baseline: 1.6724x; 1.6724x over previous
//
#include <hip/hip_runtime.h>
#include <math.h>

// ---------------------------------------------------------------------------
// CNN_88098369175791 — R6: algebraic collapse + 8 WG + 2 grid barriers.
//  td-MHA:  vA[k] = relu(sum_j attn[k][j]*vtil[j] + cvb + cbo + mc_b)
//           via u = mc0@eeg, wt = out_w^T u, wv = Wv^T wt, z_k = Wk^T qp_k.
//           (vp/av/watt/M phases eliminated.)
//  cm-MHA:  PRJ operands are rank-1 => m1/m2 collapse to o[t][c]=h[t]A[c]+B[c];
//           m0/m3 scores = wsel[t]*s1[u]+s2[u] with s1,s2 precomputed pre-bar.
// ---------------------------------------------------------------------------

#define NWG 8
#define NT  1024

constexpr int WLEN = 140;
constexpr int TDN  = 14;
constexpr int NOFC = 119;

// ---------------- global arena (floats; at d_ws + 512 B) -------------------
constexpr int G_V16 = 0;     // [32]
constexpr int G_O   = 64;    // [4][119][16]

// ---------------- LDS arena (floats) ---------------------------------------
constexpr int EEG = 0;      // [16][119]
constexpr int WA  = 1904;   // 140
constexpr int WB  = 2044;   // 140
constexpr int LNT = 2184;   // [119][16]
constexpr int QP4 = 4088;   // [4][119]
constexpr int Z4  = 4564;   // [4][119]
constexpr int UD  = 5040;   // [119]
constexpr int WTT = 5160;   // [119]  w~ = out_w^T u
constexpr int WVV = 5280;   // [119]  wv = Wv^T w~
constexpr int VT  = 5400;   // [14]   vtil
constexpr int SC4 = 5416;   // [4][14]
constexpr int BKQ = 5472;   // [4]
constexpr int CVB = 5476, CBO = 5477, MIX = 5478;
constexpr int WGT = 5480;   // [16]
constexpr int WQK = 5500;   // [16]  heavy weQ / light weK
constexpr int WEV = 5516;   // [16]  light
constexpr int AC  = 5532, BC = 5548;   // [16] each (light)
constexpr int PKQ = 5568;   // [119][16]  heavy kp / light qp (over LNT)
constexpr int VPS = 7472;   // [119][20]  heavy vp (stride 20, f4-aligned)
constexpr int S1O = 9852;   // [119] heavy s1 / light g
constexpr int S2O = 9971;   // [119] heavy s2
constexpr int OWS = 10090;  // [256] heavy out_w TRANSPOSED [e][c]
constexpr int OBS = 10346;  // [16]
constexpr int DD  = 4088;   // head (WG0, post-bar1; QP4 region dead)
constexpr int HH  = 4328;   // head
constexpr int ARENA = 10368; // 41,472 B

struct Args {
  const float *x, *td_in_w, *td_in_b, *td_out_w, *td_out_b;
  const float *cm_in_w, *cm_in_b, *cm_out_w, *cm_out_b;
  const float *mc_w, *mc_b, *max_fc_w, *max_fc_b, *proj_w;
  const float *ln_g, *ln_b, *fc_w, *fc_b;
  const float *out1_w, *out1_b, *out2_w, *out2_b;
  float *out;
  unsigned int *bar;
  float *G;
};

__device__ __forceinline__ float sigmf(float v) {
  return 1.0f / (1.0f + __expf(-v));
}

__device__ __forceinline__ void gbar(unsigned int* p) {
  __syncthreads();
  if (threadIdx.x == 0) {
    __hip_atomic_fetch_add(p, 1u, __ATOMIC_ACQ_REL, __HIP_MEMORY_SCOPE_AGENT);
    while (__hip_atomic_load(p, __ATOMIC_RELAXED, __HIP_MEMORY_SCOPE_AGENT) < (unsigned)NWG) {
      __builtin_amdgcn_s_sleep(1);
    }
    __builtin_amdgcn_fence(__ATOMIC_ACQUIRE, "agent");
  }
  __syncthreads();
}

// 119-dot over a 16-lane group; result in ALL 16 lanes.
__device__ __forceinline__ float dot119(const float* __restrict__ w,
                                        const float* __restrict__ x,
                                        int lane16) {
  float a0 = 0.f, a1 = 0.f;
#pragma unroll
  for (int t = 0; t < 7; ++t) {
    float wv = w[lane16 + 16 * t];
    float xv = x[lane16 + 16 * t];
    if (t & 1) a1 += wv * xv; else a0 += wv * xv;
  }
  if (lane16 < 7) a0 += w[112 + lane16] * x[112 + lane16];
  float acc = a0 + a1;
#pragma unroll
  for (int m = 1; m < 16; m <<= 1) acc += __shfl_xor(acc, m);
  return acc;
}

__device__ __forceinline__ float dot16f4(const float* __restrict__ x,
                                         const float* __restrict__ w) {
  const float4* xa = (const float4*)x; const float4* wa = (const float4*)w;
  float4 x0 = xa[0], x1 = xa[1], x2 = xa[2], x3 = xa[3];
  float4 w0 = wa[0], w1 = wa[1], w2 = wa[2], w3 = wa[3];
  float d0 = x0.x*w0.x + x0.y*w0.y + x0.z*w0.z + x0.w*w0.w;
  float d1 = x1.x*w1.x + x1.y*w1.y + x1.z*w1.z + x1.w*w1.w;
  float d2 = x2.x*w2.x + x2.y*w2.y + x2.z*w2.z + x2.w*w2.w;
  float d3 = x3.x*w3.x + x3.y*w3.y + x3.z*w3.z + x3.w*w3.w;
  return (d0 + d1) + (d2 + d3);
}

__global__ __launch_bounds__(NT) void fused_cnn_kernel(Args a) {
  __shared__ __align__(16) float S[ARENA];
  const int tid = threadIdx.x;
  const int wgid = blockIdx.x;
  const int grp = tid >> 4;
  const int lane16 = tid & 15;
  float* G = a.G;

  // td roles
  const int s  = wgid >> 2;            // 0: stream A, 1: stream B
  const int i0 = (wgid & 3) * 4;       // 4 v16 slots
  const int wavs = s ? WB : WA;
  // cm roles:  wg:  0  1  2  3  4  5  6  7
  //            m :  0  0  1  2  3  3  0  3
  const int m  = (wgid == 2) ? 1 : (wgid == 3) ? 2 : (wgid < 2 || wgid == 6) ? 0 : 3;
  const int r0 = (wgid == 1 || wgid == 5) ? 40 : (wgid >= 6) ? 80 : 0;
  const int nr = (wgid == 2 || wgid == 3) ? 119 : (wgid >= 6) ? 39 : 40;
  const bool heavy = (m == 0) || (m == 3);
  const int pr = (m >= 2) ? 1 : 0;           // proj row for this m's rank-1 side
  const int wavm = (m <= 1) ? WA : WB;       // wav for this m's rank-1 side

  // ---- P0: stage eeg_q, wavA, wavB ------------------------------------
  for (int t = tid; t < 16 * NOFC; t += NT) {
    int c = t / NOFC, tt = t - c * NOFC;
    S[EEG + t] = a.x[(1 + c) * WLEN + (WLEN - NOFC) + tt];
  }
  if (tid < WLEN) {
    S[WA + tid] = a.x[tid];
    S[WB + tid] = a.x[17 * WLEN + tid];
  }
  __syncthreads();

  // ---- A: qp rows for this WG's 4 slots (weight-row reuse) -------------
  for (int e = grp; e < NOFC; e += 64) {
    const float* wrow = a.td_in_w + e * NOFC;
    float w0 = wrow[lane16], w1 = wrow[lane16 + 16], w2 = wrow[lane16 + 32],
          w3 = wrow[lane16 + 48], w4 = wrow[lane16 + 64], w5 = wrow[lane16 + 80],
          w6 = wrow[lane16 + 96];
    float wt7 = (lane16 < 7) ? wrow[112 + lane16] : 0.0f;
    float b = a.td_in_b[e];
#pragma unroll
    for (int kk = 0; kk < 4; ++kk) {
      const float* x = S + EEG + (i0 + kk) * NOFC;
      float acc = w0 * x[lane16] + w1 * x[lane16 + 16] + w2 * x[lane16 + 32]
                + w3 * x[lane16 + 48] + w4 * x[lane16 + 64] + w5 * x[lane16 + 80]
                + w6 * x[lane16 + 96];
      if (lane16 < 7) acc += wt7 * x[112 + lane16];
#pragma unroll
      for (int mm = 1; mm < 16; mm <<= 1) acc += __shfl_xor(acc, mm);
      if (lane16 == 0) S[QP4 + kk * NOFC + e] = acc + b;
    }
  }
  __syncthreads();

  // ---- B: LNT | u | z_k | bkq | weQ/weK/weV ----------------------------
  if (tid < NOFC) {                         // layernorm column t
    float xv[16]; float mu = 0.f;
#pragma unroll
    for (int c = 0; c < 16; ++c) { xv[c] = S[EEG + c * NOFC + tid]; mu += xv[c]; }
    mu *= (1.0f / 16.0f);
    float var = 0.f;
#pragma unroll
    for (int c = 0; c < 16; ++c) { float d = xv[c] - mu; var += d * d; }
    var *= (1.0f / 16.0f);
    float inv = 1.0f / sqrtf(var + 1e-5f);
#pragma unroll
    for (int c = 0; c < 16; ++c)
      S[LNT + tid * 16 + c] = (xv[c] - mu) * inv * a.ln_g[c] + a.ln_b[c];
  }
  if (tid >= 128 && tid < 128 + NOFC) {     // u[d] = sum_i mc_s[i]*eeg[i][d]
    int d = tid - 128;
    float acc = 0.f;
#pragma unroll
    for (int i = 0; i < 16; ++i) acc += a.mc_w[s * 16 + i] * S[EEG + i * NOFC + d];
    S[UD + d] = acc;
  }
  if (tid >= 256 && tid < 256 + NOFC) {     // z_k[t] = sum_e qp[k][e]*Wk[e][t]
    int t = tid - 256;
    float a0 = 0.f, a1 = 0.f, a2 = 0.f, a3 = 0.f;
    for (int e = 0; e < NOFC; ++e) {
      float w = a.td_in_w[(NOFC + e) * NOFC + t];
      a0 += S[QP4 + e] * w;
      a1 += S[QP4 + NOFC + e] * w;
      a2 += S[QP4 + 2 * NOFC + e] * w;
      a3 += S[QP4 + 3 * NOFC + e] * w;
    }
    S[Z4 + t] = a0; S[Z4 + NOFC + t] = a1;
    S[Z4 + 2 * NOFC + t] = a2; S[Z4 + 3 * NOFC + t] = a3;
  }
  if (tid >= 384 && tid < 448) {            // bkq[k] = qp[k].bk
    int kk = (tid - 384) >> 4;
    float acc = dot119(S + QP4 + kk * NOFC, a.td_in_b + NOFC, lane16);
    if (lane16 == 0) S[BKQ + kk] = acc;
  }
  if (tid >= 512 && tid < 528) {            // weQ (heavy) / weK (light)
    int e = tid - 512;
    int row = heavy ? (m * 48 + e) : (m * 48 + 16 + e);
    float acc = 0.f;
#pragma unroll
    for (int c = 0; c < 16; ++c) acc += a.proj_w[pr * 16 + c] * a.cm_in_w[row * 16 + c];
    S[WQK + e] = acc;
  }
  if (!heavy && tid >= 528 && tid < 544) {  // weV (light)
    int e = tid - 528;
    float acc = 0.f;
#pragma unroll
    for (int c = 0; c < 16; ++c) acc += a.proj_w[pr * 16 + c] * a.cm_in_w[(m * 48 + 32 + e) * 16 + c];
    S[WEV + e] = acc;
  }
  __syncthreads();

  // ---- C: w~ | cm kp/vp (heavy) or qp (light) + OW prefetch ------------
  if (tid < NOFC) {                         // w~[t] = sum_d u[d]*out_w[d][t]
    float acc = 0.f;
    for (int d = 0; d < NOFC; ++d) acc += S[UD + d] * a.td_out_w[d * NOFC + tid];
    S[WTT + tid] = acc;
  } else if (heavy) {
    for (int o = tid - 128; o < 4080; o += 896) {
      if (o < 1904) {                       // kp[u][e] over LNT
        int u = o >> 4, e = o & 15;
        S[PKQ + u * 16 + e] = dot16f4(S + LNT + u * 16, a.cm_in_w + (m * 48 + 16 + e) * 16)
                              + a.cm_in_b[m * 48 + 16 + e];
      } else if (o < 3808) {                // vp[u][e] over LNT (stride 20)
        int o2 = o - 1904, u = o2 >> 4, e = o2 & 15;
        S[VPS + u * 20 + e] = dot16f4(S + LNT + u * 16, a.cm_in_w + (m * 48 + 32 + e) * 16)
                              + a.cm_in_b[m * 48 + 32 + e];
      } else if (o < 4064) {                // out_w transposed [e][c]
        int o2 = o - 3808, c = o2 >> 4, e = o2 & 15;
        S[OWS + e * 16 + c] = a.cm_out_w[m * 256 + o2];
      } else {
        S[OBS + o - 4064] = a.cm_out_b[m * 16 + (o - 4064)];
      }
    }
  } else {
    for (int o = tid - 128; o < 1904; o += 896) {   // qp[t][e] over LNT
      int t = o >> 4, e = o & 15;
      S[PKQ + t * 16 + e] = dot16f4(S + LNT + t * 16, a.cm_in_w + (m * 48 + e) * 16)
                            + a.cm_in_b[m * 48 + e];
    }
  }
  __syncthreads();

  // ---- D: wv | td scores -----------------------------------------------
  if (tid < NOFC) {                         // wv[t] = sum_e w~[e]*Wv[e][t]
    float acc = 0.f;
    for (int e = 0; e < NOFC; ++e) acc += S[WTT + e] * a.td_in_w[(2 * NOFC + e) * NOFC + tid];
    S[WVV + tid] = acc;
  }
  if (grp >= 8 && grp < 64) {               // scores[k][j]
    int idx = grp - 8;
    if (idx < 56) {
      int kk = idx / TDN, j = idx - kk * TDN;
      float acc = dot119(S + wavs + j, S + Z4 + kk * NOFC, lane16);
      if (lane16 == 0)
        S[SC4 + kk * TDN + j] = 0.09166984970282113f * (acc + S[BKQ + kk]);
    }
  }
  __syncthreads();

  // ---- E: softmax | vtil | cvb,cbo | s1/s2 (heavy) or g,A,B (light) ----
  if (tid < 4) {                            // softmax rows (in place)
    float* r = S + SC4 + tid * TDN;
    float mx = r[0];
#pragma unroll
    for (int j = 1; j < TDN; ++j) mx = fmaxf(mx, r[j]);
    float sum = 0.f;
#pragma unroll
    for (int j = 0; j < TDN; ++j) { float p = __expf(r[j] - mx); r[j] = p; sum += p; }
    float inv = 1.0f / sum;
#pragma unroll
    for (int j = 0; j < TDN; ++j) r[j] *= inv;
  }
  if (grp >= 1 && grp < 15) {               // vtil[j] = win_j . wv
    int j = grp - 1;
    float acc = dot119(S + wavs + j, S + WVV, lane16);
    if (lane16 == 0) S[VT + j] = acc;
  }
  if (grp == 15) {                          // cvb = bv . w~
    float acc = dot119(a.td_in_b + 2 * NOFC, S + WTT, lane16);
    if (lane16 == 0) S[CVB] = acc;
  }
  if (grp == 16) {                          // cbo = u . out_b
    float acc = dot119(S + UD, a.td_out_b, lane16);
    if (lane16 == 0) S[CBO] = acc;
  }
  if (tid >= 288) {
    if (heavy) {
      int idx = tid - 288;
      if (idx < 238) {
        int u = (idx < NOFC) ? idx : idx - NOFC;
        const float* kpr = S + PKQ + u * 16;
        float acc = 0.f;
        if (idx < NOFC) {
#pragma unroll
          for (int e = 0; e < 16; ++e) acc += S[WQK + e] * kpr[e];
          S[S1O + u] = acc;
        } else {
#pragma unroll
          for (int e = 0; e < 16; ++e) acc += a.cm_in_b[m * 48 + e] * kpr[e];
          S[S2O + u] = acc;
        }
      }
    } else {
      int idx = tid - 288;
      if (idx < NOFC) {                     // g[t] = qp[t] . weK
        float acc = 0.f;
#pragma unroll
        for (int e = 0; e < 16; ++e) acc += S[PKQ + idx * 16 + e] * S[WQK + e];
        S[S1O + idx] = acc;
      } else if (idx >= 128 && idx < 144) { // A[c], B[c]
        int c = idx - 128;
        float a1 = 0.f, b1 = 0.f;
#pragma unroll
        for (int e = 0; e < 16; ++e) {
          float ow = a.cm_out_w[m * 256 + c * 16 + e];
          a1 += ow * S[WEV + e];
          b1 += ow * a.cm_in_b[m * 48 + 32 + e];
        }
        S[AC + c] = a1;
        S[BC + c] = b1 + a.cm_out_b[m * 16 + c];
      }
    }
  }
  __syncthreads();

  // ---- F: v16 slots -> G ------------------------------------------------
  if (tid < 4) {
    float acc = 0.f;
#pragma unroll
    for (int j = 0; j < TDN; ++j) acc += S[SC4 + tid * TDN + j] * S[VT + j];
    float v = acc + S[CVB] + S[CBO] + a.mc_b[s];
    G[G_V16 + s * 16 + i0 + tid] = fmaxf(v, 0.f);
  }
  gbar(a.bar + 0);

  // ---- argmax (replicated) ---------------------------------------------
  if (tid < 16) {
    float acc = a.max_fc_b[tid];
#pragma unroll
    for (int c = 0; c < 32; ++c) acc += a.max_fc_w[tid * 32 + c] * G[G_V16 + c];
    S[WGT + tid] = fmaxf(acc, 0.f);
  }
  __syncthreads();
  if (tid == 0) {
    float best = S[WGT]; int mi = 0;
    for (int r = 1; r < 16; ++r) {
      float w = S[WGT + r];
      if (w > best) { best = w; mi = r; }
    }
    if (mi > TDN - 1) mi = TDN - 1;         // jnp.take clamps OOB
    S[MIX] = (float)mi;
  }
  __syncthreads();

  // ---- H: cm attention --------------------------------------------------
  {
    const int mi = (int)S[MIX];
    if (heavy) {
      if (grp < nr) {
        const int t = r0 + grp;
        const float wsel = S[wavm + t + mi];
        float p[8];
        float mx = -1e30f;
#pragma unroll
        for (int cc = 0; cc < 8; ++cc) {
          int u = lane16 + cc * 16;
          float sc = (u < NOFC) ? 0.25f * (wsel * S[S1O + u] + S[S2O + u]) : -1e30f;
          p[cc] = sc;
          mx = fmaxf(mx, sc);
        }
#pragma unroll
        for (int d = 1; d < 16; d <<= 1) mx = fmaxf(mx, __shfl_xor(mx, d));
        float sum = 0.f;
#pragma unroll
        for (int cc = 0; cc < 8; ++cc) { p[cc] = __expf(p[cc] - mx); sum += p[cc]; }
#pragma unroll
        for (int d = 1; d < 16; d <<= 1) sum += __shfl_xor(sum, d);
        float inv = 1.0f / sum;

        float oa[16];
#pragma unroll
        for (int e = 0; e < 16; ++e) oa[e] = 0.f;
#pragma unroll
        for (int cc = 0; cc < 8; ++cc) {
          int u = lane16 + cc * 16;
          if (u < NOFC) {
            const float4* v4 = (const float4*)(S + VPS + u * 20);
            float4 v0 = v4[0], v1 = v4[1], v2 = v4[2], v3 = v4[3];
            float pv = p[cc];
            oa[0] += pv*v0.x; oa[1] += pv*v0.y; oa[2] += pv*v0.z; oa[3] += pv*v0.w;
            oa[4] += pv*v1.x; oa[5] += pv*v1.y; oa[6] += pv*v1.z; oa[7] += pv*v1.w;
            oa[8] += pv*v2.x; oa[9] += pv*v2.y; oa[10] += pv*v2.z; oa[11] += pv*v2.w;
            oa[12] += pv*v3.x; oa[13] += pv*v3.y; oa[14] += pv*v3.z; oa[15] += pv*v3.w;
          }
        }
#pragma unroll
        for (int e = 0; e < 16; ++e) {
#pragma unroll
          for (int d = 1; d < 16; d <<= 1) oa[e] += __shfl_xor(oa[e], d);
          oa[e] *= inv;
        }
        // out-proj, channel = lane16 (OWS transposed: no bank conflict)
        float accp = S[OBS + lane16];
#pragma unroll
        for (int e = 0; e < 16; ++e) accp += oa[e] * S[OWS + e * 16 + lane16];
        G[G_O + (m * NOFC + t) * 16 + lane16] = accp;
      }
    } else {
      for (int r = grp; r < NOFC; r += 64) {
        const float gt = S[S1O + r];
        float s0 = 0.f, s1a = 0.f;
#pragma unroll
        for (int cc = 0; cc < 8; ++cc) {
          int u = lane16 + cc * 16;
          if (u < NOFC) {
            float w = S[wavm + u + mi];
            float e1 = __expf(0.25f * gt * w);
            s0 += e1; s1a += e1 * w;
          }
        }
#pragma unroll
        for (int d = 1; d < 16; d <<= 1) {
          s0 += __shfl_xor(s0, d);
          s1a += __shfl_xor(s1a, d);
        }
        float h = s1a / s0;
        G[G_O + (m * NOFC + r) * 16 + lane16] = h * S[AC + lane16] + S[BC + lane16];
      }
    }
  }
  gbar(a.bar + 16);

  // ---- I: head (WG0) ----------------------------------------------------
  if (wgid == 0) {
    for (int o = tid; o < 2 * NOFC; o += NT) {
      int half = o / NOFC, t = o - half * NOFC;
      const float* A = G + G_O + ((half ? 3 : 0) * NOFC + t) * 16;
      const float* B = G + G_O + ((half ? 2 : 1) * NOFC + t) * 16;
      float acc = 0.f;
#pragma unroll
      for (int c = 0; c < 16; ++c) acc += A[c] * B[c];
      S[DD + o] = sigmf(a.fc_w[half] * acc + a.fc_b[half]);
    }
    __syncthreads();
    for (int o = grp; o < NOFC; o += 64) {  // out1: 238-dot
      const float* wrow = a.out1_w + o * 238;
      float a0 = 0.f, a1 = 0.f;
#pragma unroll
      for (int t = 0; t < 14; ++t) {
        float wv = wrow[lane16 + 16 * t];
        float xv = S[DD + lane16 + 16 * t];
        if (t & 1) a1 += wv * xv; else a0 += wv * xv;
      }
      if (lane16 < 14) a0 += wrow[224 + lane16] * S[DD + 224 + lane16];
      float acc = a0 + a1;
#pragma unroll
      for (int mm = 1; mm < 16; mm <<= 1) acc += __shfl_xor(acc, mm);
      if (lane16 == 0) S[HH + o] = sigmf(acc + a.out1_b[o]);
    }
    __syncthreads();
    if (tid < 32) {
      int o2 = tid >> 4;
      const float* wrow = a.out2_w + o2 * NOFC;
      float a0 = 0.f;
#pragma unroll
      for (int t = 0; t < 8; ++t) {
        int idx = lane16 + 16 * t;
        if (idx < NOFC) a0 += wrow[idx] * S[HH + idx];
      }
      float acc = a0;
#pragma unroll
      for (int mm = 1; mm < 16; mm <<= 1) acc += __shfl_xor(acc, mm);
      if (lane16 == 0) a.out[o2] = sigmf(acc + a.out2_b[o2]);
    }
  }
}

extern "C" void kernel_launch(void* const* d_in, const int* in_sizes, int n_in,
                              void* d_out, int out_size, void* d_ws, size_t ws_size,
                              hipStream_t stream) {
  Args a;
  a.x        = (const float*)d_in[0];
  a.td_in_w  = (const float*)d_in[1];
  a.td_in_b  = (const float*)d_in[2];
  a.td_out_w = (const float*)d_in[3];
  a.td_out_b = (const float*)d_in[4];
  a.cm_in_w  = (const float*)d_in[5];
  a.cm_in_b  = (const float*)d_in[6];
  a.cm_out_w = (const float*)d_in[7];
  a.cm_out_b = (const float*)d_in[8];
  a.mc_w     = (const float*)d_in[9];
  a.mc_b     = (const float*)d_in[10];
  a.max_fc_w = (const float*)d_in[11];
  a.max_fc_b = (const float*)d_in[12];
  a.proj_w   = (const float*)d_in[13];
  a.ln_g     = (const float*)d_in[14];
  a.ln_b     = (const float*)d_in[15];
  a.fc_w     = (const float*)d_in[16];
  a.fc_b     = (const float*)d_in[17];
  a.out1_w   = (const float*)d_in[18];
  a.out1_b   = (const float*)d_in[19];
  a.out2_w   = (const float*)d_in[20];
  a.out2_b   = (const float*)d_in[21];
  a.out      = (float*)d_out;
  a.bar      = (unsigned int*)d_ws;
  a.G        = (float*)((char*)d_ws + 512);

  hipMemsetAsync(d_ws, 0, 512, stream);
  fused_cnn_kernel<<<dim3(NWG), dim3(NT), 0, stream>>>(a);
}

// Round 7
// 34.664 us; speedup vs baseline: 1.7392x; 1.0400x over previous
//
#include <hip/hip_runtime.h>
#include <math.h>

// ---------------------------------------------------------------------------
// CNN_88098369175791 — R7: full tail collapse.
//  * light cm-MHAs folded into heavy WGs via d0[t]=h1[t]*(o0.A1)+(o0.B1)
//  * m0/m3 rows split over 4 WGs each (30 rows/WG)
//  * head distributed: 15 out1 rows/WG (LDS-prefetched), out2 via atomicAdd
//  * register argmax, no softmax max-subtraction (scores bounded)
// ---------------------------------------------------------------------------

#define NWG 8
#define NT  1024

constexpr int WLEN = 140;
constexpr int TDN  = 14;
constexpr int NOFC = 119;

// global arena (floats; at d_ws + 512 B); d_ws[0..127]=barriers, ACC@128B, DONE@192B
constexpr int G_V16 = 0;     // [32]
constexpr int G_DD  = 64;    // [238]

// ---------------- LDS arena (floats) ---------------------------------------
constexpr int EEG = 0;      // [16][119]
constexpr int WA  = 1904;   // 140
constexpr int WB  = 2044;   // 140
constexpr int LNT = 2184;   // [119][16]
constexpr int QP4 = 4088;   // [4][119]
constexpr int Z4  = 4564;   // [4][119]
constexpr int UD  = 5040;   // [119]
constexpr int WTT = 5160;   // [119]
constexpr int WVV = 5280;   // [119]
constexpr int VT  = 5400;   // [14]
constexpr int SC4 = 5416;   // [4][14]
constexpr int BKQ = 5472;   // [4]
constexpr int CVB = 5476, CBO = 5477;
constexpr int WQH = 5480;   // [16] heavy weQ
constexpr int WKL = 5496;   // [16] light weK
constexpr int WVL = 5512;   // [16] light weV
constexpr int WQT = 5528;   // [16] light wq~
constexpr int CST = 5544;   // [1]
constexpr int AC  = 5548;   // [16]
constexpr int BC  = 5564;   // [16]
constexpr int G1L = 5580;   // [30]
constexpr int MXT = 5612;   // [512] max_fc_w transposed [c][16]
constexpr int MXB = 6124;   // [16]
constexpr int KPH = 6144;   // [119][16]
constexpr int VPS = 8048;   // [119][20] (f4-aligned, padded)
constexpr int S1H = 10428;  // [119]
constexpr int S2H = 10547;  // [119]
constexpr int OWS = 10668;  // [256] heavy out_w transposed [e][c]
constexpr int OBS = 10924;  // [16]
constexpr int O1W = 10944;  // [15][240] my out1_w rows
constexpr int O1B = 14544;  // [15]
constexpr int O2WS= 14560;  // [30]  out2_w[0][mine], out2_w[1][mine]
constexpr int O2B = 14590;  // [2]
constexpr int FCW = 14592;  // [2]
constexpr int FCB = 14594;  // [2]
constexpr int DDL = 14596;  // [238]
constexpr int HHL = 14836;  // [15]
constexpr int VSL = 14852;  // [32]
constexpr int ARENA = 14884; // 59,536 B

struct Args {
  const float *x, *td_in_w, *td_in_b, *td_out_w, *td_out_b;
  const float *cm_in_w, *cm_in_b, *cm_out_w, *cm_out_b;
  const float *mc_w, *mc_b, *max_fc_w, *max_fc_b, *proj_w;
  const float *ln_g, *ln_b, *fc_w, *fc_b;
  const float *out1_w, *out1_b, *out2_w, *out2_b;
  float *out;
  unsigned int *bar;   // d_ws
  float *G;            // d_ws + 512
};

__device__ __forceinline__ float sigmf(float v) {
  return 1.0f / (1.0f + __expf(-v));
}

__device__ __forceinline__ void gbar(unsigned int* p) {
  __syncthreads();
  if (threadIdx.x == 0) {
    __hip_atomic_fetch_add(p, 1u, __ATOMIC_ACQ_REL, __HIP_MEMORY_SCOPE_AGENT);
    while (__hip_atomic_load(p, __ATOMIC_RELAXED, __HIP_MEMORY_SCOPE_AGENT) < (unsigned)NWG) {
      __builtin_amdgcn_s_sleep(1);
    }
    __builtin_amdgcn_fence(__ATOMIC_ACQUIRE, "agent");
  }
  __syncthreads();
}

__device__ __forceinline__ float dot119(const float* __restrict__ w,
                                        const float* __restrict__ x,
                                        int lane16) {
  float a0 = 0.f, a1 = 0.f;
#pragma unroll
  for (int t = 0; t < 7; ++t) {
    float wv = w[lane16 + 16 * t];
    float xv = x[lane16 + 16 * t];
    if (t & 1) a1 += wv * xv; else a0 += wv * xv;
  }
  if (lane16 < 7) a0 += w[112 + lane16] * x[112 + lane16];
  float acc = a0 + a1;
#pragma unroll
  for (int m = 1; m < 16; m <<= 1) acc += __shfl_xor(acc, m);
  return acc;
}

__device__ __forceinline__ float dot16f4(const float* __restrict__ x,
                                         const float* __restrict__ w) {
  const float4* xa = (const float4*)x; const float4* wa = (const float4*)w;
  float4 x0 = xa[0], x1 = xa[1], x2 = xa[2], x3 = xa[3];
  float4 w0 = wa[0], w1 = wa[1], w2 = wa[2], w3 = wa[3];
  float d0 = x0.x*w0.x + x0.y*w0.y + x0.z*w0.z + x0.w*w0.w;
  float d1 = x1.x*w1.x + x1.y*w1.y + x1.z*w1.z + x1.w*w1.w;
  float d2 = x2.x*w2.x + x2.y*w2.y + x2.z*w2.z + x2.w*w2.w;
  float d3 = x3.x*w3.x + x3.y*w3.y + x3.z*w3.z + x3.w*w3.w;
  return (d0 + d1) + (d2 + d3);
}

__global__ __launch_bounds__(NT) void fused_cnn_kernel(Args a) {
  __shared__ __align__(16) float S[ARENA];
  const int tid = threadIdx.x;
  const int wgid = blockIdx.x;
  const int grp = tid >> 4;
  const int lane16 = tid & 15;
  float* G = a.G;

  const int s  = wgid >> 2;              // 0: A-stream (m0), 1: B-stream (m3)
  const int i0 = (wgid & 3) * 4;         // v16 slots
  const int mh = s ? 3 : 0;              // heavy cm-MHA
  const int lm = s ? 2 : 1;              // paired light cm-MHA
  const int q4 = wgid & 3;
  const int r0 = q4 * 30;
  const int nr = (q4 == 3) ? 29 : 30;
  const int wavX = s ? WB : WA;          // proj stream for both heavy-q and light-kv

  // ---- P0: stage x + prefetch argmax & head weights --------------------
  for (int t = tid; t < 16 * NOFC; t += NT) {
    int c = t / NOFC, tt = t - c * NOFC;
    S[EEG + t] = a.x[(1 + c) * WLEN + (WLEN - NOFC) + tt];
  }
  if (tid < WLEN) {
    S[WA + tid] = a.x[tid];
    S[WB + tid] = a.x[17 * WLEN + tid];
  }
  if (tid < 512) {                       // max_fc_w transposed [c][16]
    int t16 = tid >> 5, c32 = tid & 31;
    S[MXT + c32 * 16 + t16] = a.max_fc_w[tid];
  }
  if (tid < 16)  S[MXB + tid] = a.max_fc_b[tid];
  for (int idx = tid; idx < 15 * 238; idx += NT) {    // my out1_w rows
    int rl = idx / 238, c = idx - rl * 238;
    int r = wgid * 15 + rl;
    S[O1W + rl * 240 + c] = (r < NOFC) ? a.out1_w[r * 238 + c] : 0.0f;
  }
  if (tid < 15) {
    int r = wgid * 15 + tid;
    S[O1B + tid] = (r < NOFC) ? a.out1_b[r] : 0.0f;
  }
  if (tid < 30) {
    int o = tid / 15, j = tid - o * 15;
    int r = wgid * 15 + j;
    S[O2WS + tid] = (r < NOFC) ? a.out2_w[o * NOFC + r] : 0.0f;
  }
  if (tid < 2) {
    S[O2B + tid] = a.out2_b[tid];
    S[FCW + tid] = a.fc_w[tid];
    S[FCB + tid] = a.fc_b[tid];
  }
  __syncthreads();

  // ---- A: qp (4 rows, weight-row reuse) + u ----------------------------
  for (int e = grp; e < NOFC; e += 64) {
    const float* wrow = a.td_in_w + e * NOFC;
    float w0 = wrow[lane16], w1 = wrow[lane16 + 16], w2 = wrow[lane16 + 32],
          w3 = wrow[lane16 + 48], w4 = wrow[lane16 + 64], w5 = wrow[lane16 + 80],
          w6 = wrow[lane16 + 96];
    float wt7 = (lane16 < 7) ? wrow[112 + lane16] : 0.0f;
    float b = a.td_in_b[e];
#pragma unroll
    for (int kk = 0; kk < 4; ++kk) {
      const float* x = S + EEG + (i0 + kk) * NOFC;
      float acc = w0 * x[lane16] + w1 * x[lane16 + 16] + w2 * x[lane16 + 32]
                + w3 * x[lane16 + 48] + w4 * x[lane16 + 64] + w5 * x[lane16 + 80]
                + w6 * x[lane16 + 96];
      if (lane16 < 7) acc += wt7 * x[112 + lane16];
#pragma unroll
      for (int mm = 1; mm < 16; mm <<= 1) acc += __shfl_xor(acc, mm);
      if (lane16 == 0) S[QP4 + kk * NOFC + e] = acc + b;
    }
  }
  if (grp >= 55) {                        // u[d] = mc_w[s] . eeg[:,d]
    int d = (grp - 55) * 16 + lane16;
    if (d < NOFC) {
      float acc = 0.f;
#pragma unroll
      for (int i = 0; i < 16; ++i) acc += a.mc_w[s * 16 + i] * S[EEG + i * NOFC + d];
      S[UD + d] = acc;
    }
  }
  __syncthreads();

  // ---- B: LNT | z_k | bkq | w~ | we-vectors | td scores ----------------
  if (tid < NOFC) {
    float xv[16]; float mu = 0.f;
#pragma unroll
    for (int c = 0; c < 16; ++c) { xv[c] = S[EEG + c * NOFC + tid]; mu += xv[c]; }
    mu *= (1.0f / 16.0f);
    float var = 0.f;
#pragma unroll
    for (int c = 0; c < 16; ++c) { float d = xv[c] - mu; var += d * d; }
    var *= (1.0f / 16.0f);
    float inv = 1.0f / sqrtf(var + 1e-5f);
#pragma unroll
    for (int c = 0; c < 16; ++c)
      S[LNT + tid * 16 + c] = (xv[c] - mu) * inv * a.ln_g[c] + a.ln_b[c];
  } else if (tid >= 128 && tid < 128 + NOFC) {   // z_k
    int t = tid - 128;
    float a0 = 0.f, a1 = 0.f, a2 = 0.f, a3 = 0.f;
    for (int e = 0; e < NOFC; ++e) {
      float w = a.td_in_w[(NOFC + e) * NOFC + t];
      a0 += S[QP4 + e] * w;
      a1 += S[QP4 + NOFC + e] * w;
      a2 += S[QP4 + 2 * NOFC + e] * w;
      a3 += S[QP4 + 3 * NOFC + e] * w;
    }
    S[Z4 + t] = a0; S[Z4 + NOFC + t] = a1;
    S[Z4 + 2 * NOFC + t] = a2; S[Z4 + 3 * NOFC + t] = a3;
  } else if (tid >= 256 && tid < 320) {          // bkq
    int kk = (tid - 256) >> 4;
    float acc = dot119(S + QP4 + kk * NOFC, a.td_in_b + NOFC, lane16);
    if (lane16 == 0) S[BKQ + kk] = acc;
  } else if (tid >= 320 && tid < 320 + NOFC) {   // w~[t] = u . out_w[:,t]
    int t = tid - 320;
    float acc = 0.f;
    for (int d = 0; d < NOFC; ++d) acc += S[UD + d] * a.td_out_w[d * NOFC + t];
    S[WTT + t] = acc;
  } else if (tid >= 448 && tid < 464) {          // weQ heavy
    int e = tid - 448;
    float acc = 0.f;
#pragma unroll
    for (int c = 0; c < 16; ++c) acc += a.proj_w[s * 16 + c] * a.cm_in_w[(mh * 48 + e) * 16 + c];
    S[WQH + e] = acc;
  } else if (tid >= 464 && tid < 480) {          // weK light
    int e = tid - 464;
    float acc = 0.f;
#pragma unroll
    for (int c = 0; c < 16; ++c) acc += a.proj_w[s * 16 + c] * a.cm_in_w[(lm * 48 + 16 + e) * 16 + c];
    S[WKL + e] = acc;
  } else if (tid >= 480 && tid < 496) {          // weV light
    int e = tid - 480;
    float acc = 0.f;
#pragma unroll
    for (int c = 0; c < 16; ++c) acc += a.proj_w[s * 16 + c] * a.cm_in_w[(lm * 48 + 32 + e) * 16 + c];
    S[WVL + e] = acc;
  }
  if (grp >= 36) {                               // td scores, 2 rounds
#pragma unroll
    for (int rnd = 0; rnd < 2; ++rnd) {
      int idx = (grp - 36) + rnd * 28;
      if (idx < 56) {
        int kk = idx / TDN, j = idx - kk * TDN;
        float acc = dot119(S + wavX + j, S + Z4 + kk * NOFC, lane16);
        if (lane16 == 0)
          S[SC4 + kk * TDN + j] = 0.09166984970282113f * (acc + S[BKQ + kk]);
      }
    }
  }
  __syncthreads();

  // ---- C: wv | softmax | wq~ | cst | A/B | cvb/cbo | kp/vp/OWS ---------
  if (tid < NOFC) {                              // wv[t] = w~ . Wv[:,t]
    float acc = 0.f;
    for (int e = 0; e < NOFC; ++e) acc += S[WTT + e] * a.td_in_w[(2 * NOFC + e) * NOFC + tid];
    S[WVV + tid] = acc;
  } else if (tid >= 120 && tid < 124) {          // td softmax (no max-sub needed? keep stable form)
    int k = tid - 120;
    float* r = S + SC4 + k * TDN;
    float mx = r[0];
#pragma unroll
    for (int j = 1; j < TDN; ++j) mx = fmaxf(mx, r[j]);
    float sum = 0.f;
#pragma unroll
    for (int j = 0; j < TDN; ++j) { float p = __expf(r[j] - mx); r[j] = p; sum += p; }
    float inv = 1.0f / sum;
#pragma unroll
    for (int j = 0; j < TDN; ++j) r[j] *= inv;
  } else if (tid >= 128 && tid < 144) {          // wq~[c] = sum_e Wq_lm[e][c]*weK[e]
    int c = tid - 128;
    float acc = 0.f;
#pragma unroll
    for (int e = 0; e < 16; ++e) acc += a.cm_in_w[(lm * 48 + e) * 16 + c] * S[WKL + e];
    S[WQT + c] = acc;
  } else if (tid == 144) {                       // cst = bq_lm . weK
    float acc = 0.f;
#pragma unroll
    for (int e = 0; e < 16; ++e) acc += a.cm_in_b[lm * 48 + e] * S[WKL + e];
    S[CST] = acc;
  } else if (tid >= 160 && tid < 176) {          // A1[c]
    int c = tid - 160;
    float acc = 0.f;
#pragma unroll
    for (int e = 0; e < 16; ++e) acc += a.cm_out_w[lm * 256 + c * 16 + e] * S[WVL + e];
    S[AC + c] = acc;
  } else if (tid >= 176 && tid < 192) {          // B1[c]
    int c = tid - 176;
    float acc = 0.f;
#pragma unroll
    for (int e = 0; e < 16; ++e) acc += a.cm_out_w[lm * 256 + c * 16 + e] * a.cm_in_b[lm * 48 + 32 + e];
    S[BC + c] = acc + a.cm_out_b[lm * 16 + c];
  } else if (tid == 192) {                       // cvb = bv_td . w~
    float acc = 0.f;
    for (int e = 0; e < NOFC; ++e) acc += a.td_in_b[2 * NOFC + e] * S[WTT + e];
    S[CVB] = acc;
  } else if (tid == 193) {                       // cbo = u . out_b
    float acc = 0.f;
    for (int d = 0; d < NOFC; ++d) acc += S[UD + d] * a.td_out_b[d];
    S[CBO] = acc;
  }
  if (tid >= 256) {                              // kp/vp/OWS/OBS for mh
    for (int o = tid - 256; o < 4080; o += 768) {
      if (o < 1904) {
        int u = o >> 4, e = o & 15;
        S[KPH + o] = dot16f4(S + LNT + u * 16, a.cm_in_w + (mh * 48 + 16 + e) * 16)
                     + a.cm_in_b[mh * 48 + 16 + e];
      } else if (o < 3808) {
        int o2 = o - 1904, u = o2 >> 4, e = o2 & 15;
        S[VPS + u * 20 + e] = dot16f4(S + LNT + u * 16, a.cm_in_w + (mh * 48 + 32 + e) * 16)
                              + a.cm_in_b[mh * 48 + 32 + e];
      } else if (o < 4064) {
        int o2 = o - 3808, c = o2 >> 4, e = o2 & 15;
        S[OWS + e * 16 + c] = a.cm_out_w[mh * 256 + o2];
      } else {
        S[OBS + o - 4064] = a.cm_out_b[mh * 16 + (o - 4064)];
      }
    }
  }
  __syncthreads();

  // ---- D: vtil | g1 (own rows) | s1/s2 ---------------------------------
  if (grp < TDN) {
    float acc = dot119(S + wavX + grp, S + WVV, lane16);
    if (lane16 == 0) S[VT + grp] = acc;
  }
  if (tid >= 256 && tid < 256 + 30) {
    int rl = tid - 256;
    if (rl < nr) {
      int t = r0 + rl;
      float acc = S[CST];
#pragma unroll
      for (int c = 0; c < 16; ++c) acc += S[LNT + t * 16 + c] * S[WQT + c];
      S[G1L + rl] = acc;
    }
  }
  if (tid >= 512 && tid < 512 + 238) {
    int idx = tid - 512;
    int u = (idx < NOFC) ? idx : idx - NOFC;
    const float* kpr = S + KPH + u * 16;
    float acc = 0.f;
    if (idx < NOFC) {
#pragma unroll
      for (int e = 0; e < 16; ++e) acc += S[WQH + e] * kpr[e];
      S[S1H + u] = acc;
    } else {
#pragma unroll
      for (int e = 0; e < 16; ++e) acc += a.cm_in_b[mh * 48 + e] * kpr[e];
      S[S2H + u] = acc;
    }
  }
  __syncthreads();

  // ---- E: v16 -> G ------------------------------------------------------
  if (tid < 4) {
    float acc = 0.f;
#pragma unroll
    for (int j = 0; j < TDN; ++j) acc += S[SC4 + tid * TDN + j] * S[VT + j];
    float v = acc + S[CVB] + S[CBO] + a.mc_b[s];
    G[G_V16 + s * 16 + i0 + tid] = fmaxf(v, 0.f);
  }
  gbar(a.bar + 0);

  // ---- argmax: stage v16 then per-group register argmax -----------------
  if (tid < 32) S[VSL + tid] = G[G_V16 + tid];
  __syncthreads();
  int mi;
  {
    float wl = S[MXB + lane16];
#pragma unroll
    for (int c = 0; c < 32; ++c) wl += S[MXT + c * 16 + lane16] * S[VSL + c];
    wl = fmaxf(wl, 0.f);
    float mx = wl;
#pragma unroll
    for (int d = 1; d < 16; d <<= 1) mx = fmaxf(mx, __shfl_xor(mx, d));
    int cand = (wl == mx) ? lane16 : 99;
#pragma unroll
    for (int d = 1; d < 16; d <<= 1) cand = min(cand, __shfl_xor(cand, d));
    mi = min(cand, TDN - 1);
  }

  // ---- attention rows: o0 row + fold light MHA -> dd --------------------
  if (grp < nr) {
    const int t = r0 + grp;
    const float wselq = S[wavX + t + mi];
    float p[8];
    float sum = 0.f;
#pragma unroll
    for (int cc = 0; cc < 8; ++cc) {
      int u = lane16 + cc * 16;
      float e1 = 0.f;
      if (u < NOFC)
        e1 = __expf(0.25f * (wselq * S[S1H + u] + S[S2H + u]));
      p[cc] = e1;
      sum += e1;
    }
#pragma unroll
    for (int d = 1; d < 16; d <<= 1) sum += __shfl_xor(sum, d);
    float inv = 1.0f / sum;

    float oa[16];
#pragma unroll
    for (int e = 0; e < 16; ++e) oa[e] = 0.f;
#pragma unroll
    for (int cc = 0; cc < 8; ++cc) {
      int u = lane16 + cc * 16;
      if (u < NOFC) {
        const float4* v4 = (const float4*)(S + VPS + u * 20);
        float4 v0 = v4[0], v1 = v4[1], v2 = v4[2], v3 = v4[3];
        float pv = p[cc];
        oa[0] += pv*v0.x; oa[1] += pv*v0.y; oa[2] += pv*v0.z; oa[3] += pv*v0.w;
        oa[4] += pv*v1.x; oa[5] += pv*v1.y; oa[6] += pv*v1.z; oa[7] += pv*v1.w;
        oa[8] += pv*v2.x; oa[9] += pv*v2.y; oa[10] += pv*v2.z; oa[11] += pv*v2.w;
        oa[12] += pv*v3.x; oa[13] += pv*v3.y; oa[14] += pv*v3.z; oa[15] += pv*v3.w;
      }
    }
#pragma unroll
    for (int e = 0; e < 16; ++e) {
#pragma unroll
      for (int d = 1; d < 16; d <<= 1) oa[e] += __shfl_xor(oa[e], d);
    }
    // out-proj channel lane16
    float oc = S[OBS + lane16];
#pragma unroll
    for (int e = 0; e < 16; ++e) oc += oa[e] * inv * S[OWS + e * 16 + lane16];
    // fold light MHA: d = h * (o.A1) + (o.B1)
    float dA = oc * S[AC + lane16];
    float dB = oc * S[BC + lane16];
#pragma unroll
    for (int d = 1; d < 16; d <<= 1) {
      dA += __shfl_xor(dA, d);
      dB += __shfl_xor(dB, d);
    }
    const float g = S[G1L + grp];
    float s0 = 0.f, s1a = 0.f;
#pragma unroll
    for (int cc = 0; cc < 8; ++cc) {
      int u = lane16 + cc * 16;
      if (u < NOFC) {
        float w = S[wavX + u + mi];
        float e1 = __expf(0.25f * g * w);
        s0 += e1; s1a += e1 * w;
      }
    }
#pragma unroll
    for (int d = 1; d < 16; d <<= 1) {
      s0 += __shfl_xor(s0, d);
      s1a += __shfl_xor(s1a, d);
    }
    float h = s1a / s0;
    float dval = h * dA + dB;
    if (lane16 == 0)
      G[G_DD + s * NOFC + t] = sigmf(S[FCW + s] * dval + S[FCB + s]);
  }
  gbar(a.bar + 16);

  // ---- head: dd -> LDS, 15 out1 rows, out2 partial via atomics ----------
  if (tid < 238) S[DDL + tid] = G[G_DD + tid];
  __syncthreads();
  if (grp < 15) {
    int r = wgid * 15 + grp;
    float acc = 0.f;
#pragma unroll
    for (int k = 0; k < 15; ++k) {
      int c = lane16 + 16 * k;
      if (c < 238) acc += S[O1W + grp * 240 + c] * S[DDL + c];
    }
#pragma unroll
    for (int d = 1; d < 16; d <<= 1) acc += __shfl_xor(acc, d);
    if (lane16 == 0)
      S[HHL + grp] = (r < NOFC) ? sigmf(acc + S[O1B + grp]) : 0.0f;
  }
  __syncthreads();
  if (tid == 0) {
    float p0 = 0.f, p1 = 0.f;
#pragma unroll
    for (int j = 0; j < 15; ++j) {
      p0 += S[O2WS + j] * S[HHL + j];
      p1 += S[O2WS + 15 + j] * S[HHL + j];
    }
    float* acc = (float*)((char*)a.bar + 128);
    unsigned int* done = (unsigned int*)((char*)a.bar + 192);
    __hip_atomic_fetch_add(acc + 0, p0, __ATOMIC_RELAXED, __HIP_MEMORY_SCOPE_AGENT);
    __hip_atomic_fetch_add(acc + 1, p1, __ATOMIC_RELAXED, __HIP_MEMORY_SCOPE_AGENT);
    unsigned old = __hip_atomic_fetch_add(done, 1u, __ATOMIC_ACQ_REL, __HIP_MEMORY_SCOPE_AGENT);
    if (old == NWG - 1) {
      __builtin_amdgcn_fence(__ATOMIC_ACQUIRE, "agent");
      float a0 = __hip_atomic_load(acc + 0, __ATOMIC_RELAXED, __HIP_MEMORY_SCOPE_AGENT);
      float a1 = __hip_atomic_load(acc + 1, __ATOMIC_RELAXED, __HIP_MEMORY_SCOPE_AGENT);
      a.out[0] = sigmf(a0 + S[O2B + 0]);
      a.out[1] = sigmf(a1 + S[O2B + 1]);
    }
  }
}

extern "C" void kernel_launch(void* const* d_in, const int* in_sizes, int n_in,
                              void* d_out, int out_size, void* d_ws, size_t ws_size,
                              hipStream_t stream) {
  Args a;
  a.x        = (const float*)d_in[0];
  a.td_in_w  = (const float*)d_in[1];
  a.td_in_b  = (const float*)d_in[2];
  a.td_out_w = (const float*)d_in[3];
  a.td_out_b = (const float*)d_in[4];
  a.cm_in_w  = (const float*)d_in[5];
  a.cm_in_b  = (const float*)d_in[6];
  a.cm_out_w = (const float*)d_in[7];
  a.cm_out_b = (const float*)d_in[8];
  a.mc_w     = (const float*)d_in[9];
  a.mc_b     = (const float*)d_in[10];
  a.max_fc_w = (const float*)d_in[11];
  a.max_fc_b = (const float*)d_in[12];
  a.proj_w   = (const float*)d_in[13];
  a.ln_g     = (const float*)d_in[14];
  a.ln_b     = (const float*)d_in[15];
  a.fc_w     = (const float*)d_in[16];
  a.fc_b     = (const float*)d_in[17];
  a.out1_w   = (const float*)d_in[18];
  a.out1_b   = (const float*)d_in[19];
  a.out2_w   = (const float*)d_in[20];
  a.out2_b   = (const float*)d_in[21];
  a.out      = (float*)d_out;
  a.bar      = (unsigned int*)d_ws;
  a.G        = (float*)((char*)d_ws + 512);

  // zero barriers + out2 accumulators + done counter each call.
  hipMemsetAsync(d_ws, 0, 512, stream);
  fused_cnn_kernel<<<dim3(NWG), dim3(NT), 0, stream>>>(a);
}